// Round 1
// baseline (152.403 us; speedup 1.0000x reference)
//
#include <hip/hip_runtime.h>

// SparseEmbedding forward: out[n, :] = weight[indices[n], :]
//   weight : [1'000'000, 128] fp32  (512 B per row)
//   indices: [4096, 200] int (flat N = 819'200)
//   out    : [N, 128] fp32
//
// Layout: each row is 32 x float4. 32 consecutive lanes own one row ->
// one fully-coalesced 512 B load + 512 B store per row. Index load is
// the same address across the 32 lanes of a row-group (L1 broadcast).

constexpr int VEC_PER_ROW = 32;  // 128 floats / 4 per float4

__global__ __launch_bounds__(256) void sparse_embedding_gather(
    const float4* __restrict__ weight,   // [1e6 * 32] float4
    const int*    __restrict__ indices,  // [N]
    float4*       __restrict__ out,      // [N * 32] float4
    int total_vec)                       // N * 32
{
    int i = blockIdx.x * 256 + threadIdx.x;
    if (i >= total_vec) return;

    int row  = i >> 5;        // which output row
    int lane = i & 31;        // which float4 within the row

    long long src = (long long)indices[row] * VEC_PER_ROW + lane;
    out[i] = weight[src];
}

extern "C" void kernel_launch(void* const* d_in, const int* in_sizes, int n_in,
                              void* d_out, int out_size, void* d_ws, size_t ws_size,
                              hipStream_t stream) {
    const float4* weight  = (const float4*)d_in[0];
    const int*    indices = (const int*)d_in[1];
    float4*       out     = (float4*)d_out;

    const int n_rows    = in_sizes[1];          // 819'200
    const int total_vec = n_rows * VEC_PER_ROW; // 26'214'400

    const int block  = 256;
    const int blocks = (total_vec + block - 1) / block;

    sparse_embedding_gather<<<blocks, block, 0, stream>>>(
        weight, indices, out, total_vec);
}

// Round 3
// 139.183 us; speedup vs baseline: 1.0950x; 1.0950x over previous
//
#include <hip/hip_runtime.h>

// SparseEmbedding forward: out[n, :] = weight[indices[n], :]
//   weight : [1'000'000, 128] fp32  (512 B per row)
//   indices: [4096, 200] int (flat N = 819'200)
//   out    : [N, 128] fp32
//
// Layout: 32 consecutive lanes own one row (32 x float4 = 512 B) ->
// fully coalesced load + store. Index is broadcast across the row-group.
//
// Stores are NON-TEMPORAL: the output is write-once and never re-read,
// so keep it out of L2/L3 and leave the cache for duplicate weight rows
// (~260K of the 819K gathers are repeats; caching them saves ~130 MB of
// HBM fetch). Uses a native clang vector type because the builtin
// rejects HIP_vector_type<float,4>.

typedef float f32x4 __attribute__((ext_vector_type(4)));

constexpr int VEC_PER_ROW = 32;  // 128 floats / 4 per float4

__global__ __launch_bounds__(256) void sparse_embedding_gather(
    const f32x4* __restrict__ weight,   // [1e6 * 32] f32x4
    const int*   __restrict__ indices,  // [N]
    f32x4*       __restrict__ out,      // [N * 32] f32x4
    int total_vec)                      // N * 32
{
    int i = blockIdx.x * 256 + threadIdx.x;
    if (i >= total_vec) return;

    int row  = i >> 5;        // which output row
    int lane = i & 31;        // which float4 within the row

    long long src = (long long)indices[row] * VEC_PER_ROW + lane;
    f32x4 v = weight[src];
    __builtin_nontemporal_store(v, &out[i]);
}

extern "C" void kernel_launch(void* const* d_in, const int* in_sizes, int n_in,
                              void* d_out, int out_size, void* d_ws, size_t ws_size,
                              hipStream_t stream) {
    const f32x4* weight  = (const f32x4*)d_in[0];
    const int*   indices = (const int*)d_in[1];
    f32x4*       out     = (f32x4*)d_out;

    const int n_rows    = in_sizes[1];          // 819'200
    const int total_vec = n_rows * VEC_PER_ROW; // 26'214'400

    const int block  = 256;
    const int blocks = (total_vec + block - 1) / block;

    sparse_embedding_gather<<<blocks, block, 0, stream>>>(
        weight, indices, out, total_vec);
}